// Round 4
// baseline (192.754 us; speedup 1.0000x reference)
//
#include <hip/hip_runtime.h>
#include <hip/hip_bf16.h>
#include <stdint.h>

#define LOG2E 1.44269504088896340736f

typedef float f32x4 __attribute__((ext_vector_type(4)));
typedef __bf16 bf16x8 __attribute__((ext_vector_type(8)));

__device__ __forceinline__ void g2lds16(const void* g, void* l) {
  __builtin_amdgcn_global_load_lds(
      (__attribute__((address_space(1))) unsigned int*)g,
      (__attribute__((address_space(3))) unsigned int*)l,
      16, 0, 0);
}

__device__ __forceinline__ unsigned short f2bf_u(float f) {
  __bf16 h = (__bf16)f;
  return __builtin_bit_cast(unsigned short, h);
}

// ---------------------------------------------------------------------------
// prep_hidden: one block per row i (B*S = 8192). Converts hidden row to bf16,
// computes xu = h.U[:1024]+U[1024], xv = h.V[:1024]+V[1024].
// Stores aL[i] = (xu/8)*log2e, vArr[i] = xv.
// ---------------------------------------------------------------------------
__global__ void __launch_bounds__(256) prep_hidden(
    const float* __restrict__ hidden, const float* __restrict__ U,
    const float* __restrict__ V, unsigned short* __restrict__ hbf,
    float* __restrict__ aL, float* __restrict__ vArr) {
  int row = blockIdx.x;
  int tid = threadIdx.x;
  const float* hr = hidden + (size_t)row * 1024;
  float4 x = *(const float4*)&hr[tid * 4];
  float4 u = *(const float4*)&U[tid * 4];
  float4 v = *(const float4*)&V[tid * 4];
  ushort4 hb;
  hb.x = f2bf_u(x.x); hb.y = f2bf_u(x.y); hb.z = f2bf_u(x.z); hb.w = f2bf_u(x.w);
  *(ushort4*)&hbf[(size_t)row * 1024 + tid * 4] = hb;
  float su = x.x * u.x + x.y * u.y + x.z * u.z + x.w * u.w;
  float sv = x.x * v.x + x.y * v.y + x.z * v.z + x.w * v.w;
  for (int off = 32; off > 0; off >>= 1) {
    su += __shfl_down(su, off);
    sv += __shfl_down(sv, off);
  }
  __shared__ float red[8];
  int lane = tid & 63, w = tid >> 6;
  if (lane == 0) { red[w] = su; red[4 + w] = sv; }
  __syncthreads();
  if (tid == 0) {
    float xu = red[0] + red[1] + red[2] + red[3] + U[1024];
    float xv = red[4] + red[5] + red[6] + red[7] + V[1024];
    aL[row] = xu * 0.125f * LOG2E;
    vArr[row] = xv;
  }
}

// ---------------------------------------------------------------------------
__global__ void __launch_bounds__(256) prep_w(const float* __restrict__ w,
                                              unsigned short* __restrict__ wbf) {
  int idx = (blockIdx.x * 256 + threadIdx.x) * 4;
  float4 x = *(const float4*)&w[idx];
  ushort4 hb;
  hb.x = f2bf_u(x.x); hb.y = f2bf_u(x.y); hb.z = f2bf_u(x.z); hb.w = f2bf_u(x.w);
  *(ushort4*)&wbf[idx] = hb;
}

// ---------------------------------------------------------------------------
// statsP: one block per row i. Mask fused (reads raw mask, scales by log2e).
// Computes row max and sum in log2 domain, then writes
// P'[i][t] = invZ*exp2(aL*v + mask*log2e - mx) as bf16.
// Each thread owns 8 consecutive t (t0 = tid*8).
// ---------------------------------------------------------------------------
__global__ void __launch_bounds__(256) statsP(
    const float* __restrict__ aL, const float* __restrict__ vArr,
    const float* __restrict__ mask, unsigned short* __restrict__ p) {
  int i = blockIdx.x;
  int tb = (i >> 11) << 11;
  int tid = threadIdx.x;
  int t0 = tid * 8;
  float a = aL[i];
  float4 v0 = *(const float4*)&vArr[tb + t0];
  float4 v1 = *(const float4*)&vArr[tb + t0 + 4];
  float4 m0 = *(const float4*)&mask[tb + t0];
  float4 m1 = *(const float4*)&mask[tb + t0 + 4];
  float s[8];
  s[0] = fmaf(a, v0.x, m0.x * LOG2E); s[1] = fmaf(a, v0.y, m0.y * LOG2E);
  s[2] = fmaf(a, v0.z, m0.z * LOG2E); s[3] = fmaf(a, v0.w, m0.w * LOG2E);
  s[4] = fmaf(a, v1.x, m1.x * LOG2E); s[5] = fmaf(a, v1.y, m1.y * LOG2E);
  s[6] = fmaf(a, v1.z, m1.z * LOG2E); s[7] = fmaf(a, v1.w, m1.w * LOG2E);
  float mloc = s[0];
#pragma unroll
  for (int u = 1; u < 8; ++u) mloc = fmaxf(mloc, s[u]);
  for (int off = 32; off > 0; off >>= 1) mloc = fmaxf(mloc, __shfl_down(mloc, off));
  __shared__ float red[8];
  __shared__ float bc[2];
  int lane = tid & 63, w = tid >> 6;
  if (lane == 0) red[w] = mloc;
  __syncthreads();
  if (tid == 0) bc[0] = fmaxf(fmaxf(red[0], red[1]), fmaxf(red[2], red[3]));
  __syncthreads();
  float mx = bc[0];
  float pe[8];
  float z = 0.f;
#pragma unroll
  for (int u = 0; u < 8; ++u) {
    pe[u] = __builtin_amdgcn_exp2f(s[u] - mx);
    z += pe[u];
  }
  for (int off = 32; off > 0; off >>= 1) z += __shfl_down(z, off);
  if (lane == 0) red[4 + w] = z;
  __syncthreads();
  if (tid == 0) bc[1] = 1.0f / (red[4] + red[5] + red[6] + red[7]);
  __syncthreads();
  float iz = bc[1];
  bf16x8 o;
#pragma unroll
  for (int u = 0; u < 8; ++u) o[u] = (__bf16)(iz * pe[u]);
  *(bf16x8*)&p[(size_t)i * 2048 + t0] = o;
}

// ---------------------------------------------------------------------------
// gemm_vl: VL = hbf @ Wbf^T + bias, stored TRANSPOSED bf16: vlt[h][i],
// pitch 8192. M=8192 N=1024 K=1024. Tile 128(M)x64(N), BK=32 -> 1024 blocks
// (4 blocks/CU). XCD swizzle: xcd = pid&7 -> m-tiles [xcd*8, xcd*8+8) x all
// 16 n-tiles; consecutive pids share the A-tile (L2-hot).
// ---------------------------------------------------------------------------
__global__ void __launch_bounds__(256) gemm_vl(
    const unsigned short* __restrict__ hbf, const unsigned short* __restrict__ wbf,
    const float* __restrict__ bias, unsigned short* __restrict__ vlt) {
  __shared__ __align__(16) char sA[128 * 64];
  __shared__ __align__(16) char sB[64 * 64];
  int tid = threadIdx.x;
  int lane = tid & 63, wave = tid >> 6;
  int pid = blockIdx.x;
  int xcd = pid & 7, kk = pid >> 3;      // kk in [0,128)
  int m0 = (xcd * 8 + (kk >> 4)) * 128;  // 64 m-tiles
  int n0 = (kk & 15) * 64;               // 16 n-tiles
  int sr = lane >> 2, sc = lane & 3;
  int wr = wave >> 1, wc = wave & 1;
  int m_ = lane & 15, q = lane >> 4;
  int e = (m_ >> 1) & 3;
  const char* arp = sA + ((wr * 64 + m_) * 64) + ((q ^ e) * 16);
  const char* brp = sB + ((wc * 32 + m_) * 64) + ((q ^ e) * 16);
  f32x4 acc[4][2] = {};
  for (int k0 = 0; k0 < 1024; k0 += 32) {
    __syncthreads();
#pragma unroll
    for (int ii = 0; ii < 2; ++ii) {
      int r0 = wave * 32 + ii * 16;
      int r = r0 + sr;
      int cg = sc ^ ((r >> 1) & 3);
      g2lds16(hbf + ((size_t)(m0 + r) * 1024 + k0 + cg * 8), sA + r0 * 64);
    }
    {
      int r0 = wave * 16;
      int r = r0 + sr;
      int cg = sc ^ ((r >> 1) & 3);
      g2lds16(wbf + ((size_t)(n0 + r) * 1024 + k0 + cg * 8), sB + r0 * 64);
    }
    __syncthreads();
    bf16x8 af[4], bfr[2];
#pragma unroll
    for (int i = 0; i < 4; ++i) af[i] = *(const bf16x8*)(arp + i * 1024);
#pragma unroll
    for (int j = 0; j < 2; ++j) bfr[j] = *(const bf16x8*)(brp + j * 1024);
#pragma unroll
    for (int i = 0; i < 4; ++i)
#pragma unroll
      for (int j = 0; j < 2; ++j)
        acc[i][j] = __builtin_amdgcn_mfma_f32_16x16x32_bf16(af[i], bfr[j], acc[i][j], 0, 0, 0);
  }
#pragma unroll
  for (int jt = 0; jt < 2; ++jt) {
    int j = n0 + wc * 32 + jt * 16 + m_;
    float bj = bias[j];
#pragma unroll
    for (int it = 0; it < 4; ++it) {
      int i = m0 + wr * 64 + it * 16 + q * 4;
      f32x4 a = acc[it][jt];
      ushort4 o;
      o.x = f2bf_u(a.x + bj); o.y = f2bf_u(a.y + bj);
      o.z = f2bf_u(a.z + bj); o.w = f2bf_u(a.w + bj);
      *(ushort4*)&vlt[(size_t)j * 8192 + i] = o;
    }
  }
}

// ---------------------------------------------------------------------------
// attn: C = P' @ VL^T-slice, full K=2048 (invZ folded into P').
// Tile 128(s)x64(h), BK=32 -> 1024 blocks (4 blocks/CU).
// XCD swizzle: xcd = pid&7 -> s-tiles [xcd*8, xcd*8+8) x all 16 h-tiles;
// consecutive pids share the P-tile (L2-hot).
// ---------------------------------------------------------------------------
__global__ void __launch_bounds__(256) attn(
    const unsigned short* __restrict__ p, const unsigned short* __restrict__ vlt,
    float* __restrict__ out) {
  __shared__ __align__(16) char sA[128 * 64];
  __shared__ __align__(16) char sB[64 * 64];
  int tid = threadIdx.x;
  int lane = tid & 63, wave = tid >> 6;
  int pid = blockIdx.x;
  int xcd = pid & 7, kk = pid >> 3;
  int i0 = (xcd * 8 + (kk >> 4)) * 128;  // s-row tile (batch-major)
  int h0 = (kk & 15) * 64;               // h tile
  int b = i0 >> 11;
  size_t toff = (size_t)b << 11;
  int sr = lane >> 2, sc = lane & 3;
  int wr = wave >> 1, wc = wave & 1;
  int m_ = lane & 15, q = lane >> 4;
  int e = (m_ >> 1) & 3;
  const char* arp = sA + ((wr * 64 + m_) * 64) + ((q ^ e) * 16);
  const char* brp = sB + ((wc * 32 + m_) * 64) + ((q ^ e) * 16);
  f32x4 acc[4][2] = {};
  for (int k0 = 0; k0 < 2048; k0 += 32) {
    __syncthreads();
#pragma unroll
    for (int ii = 0; ii < 2; ++ii) {
      int r0 = wave * 32 + ii * 16;
      int r = r0 + sr;
      int cg = sc ^ ((r >> 1) & 3);
      g2lds16(p + ((size_t)(i0 + r) * 2048 + k0 + cg * 8), sA + r0 * 64);
    }
    {
      int r0 = wave * 16;
      int r = r0 + sr;
      int cg = sc ^ ((r >> 1) & 3);
      g2lds16(vlt + ((size_t)(h0 + r) * 8192 + toff + k0 + cg * 8), sB + r0 * 64);
    }
    __syncthreads();
    bf16x8 af[4], bfr[2];
#pragma unroll
    for (int i = 0; i < 4; ++i) af[i] = *(const bf16x8*)(arp + i * 1024);
#pragma unroll
    for (int j = 0; j < 2; ++j) bfr[j] = *(const bf16x8*)(brp + j * 1024);
#pragma unroll
    for (int i = 0; i < 4; ++i)
#pragma unroll
      for (int j = 0; j < 2; ++j)
        acc[i][j] = __builtin_amdgcn_mfma_f32_16x16x32_bf16(af[i], bfr[j], acc[i][j], 0, 0, 0);
  }
#pragma unroll
  for (int it = 0; it < 4; ++it) {
    int gi = i0 + wr * 64 + it * 16 + q * 4;
#pragma unroll
    for (int jt = 0; jt < 2; ++jt) {
      int h = h0 + wc * 32 + jt * 16 + m_;
      f32x4 a = acc[it][jt];
      out[(size_t)(gi + 0) * 1024 + h] = a.x;
      out[(size_t)(gi + 1) * 1024 + h] = a.y;
      out[(size_t)(gi + 2) * 1024 + h] = a.z;
      out[(size_t)(gi + 3) * 1024 + h] = a.w;
    }
  }
}

// ---------------------------------------------------------------------------
// ws layout (peak ~50.4 MB):
//   [0, 33.5MB)        P' (bf16) -- overlaps hbf[0,16MB)+wbf[16,18MB), which
//                                   die after gemm_vl; statsP runs after.
//   [33.5MB, 50.3MB)   vlt (bf16, [1024][8192])
//   [50.3MB, 50.4MB)   aL, vArr (2 x 32KB fp32)
// ---------------------------------------------------------------------------
extern "C" void kernel_launch(void* const* d_in, const int* in_sizes, int n_in,
                              void* d_out, int out_size, void* d_ws, size_t ws_size,
                              hipStream_t stream) {
  const float* hidden = (const float*)d_in[0];
  const float* mask   = (const float*)d_in[1];
  const float* vw     = (const float*)d_in[2];
  const float* vb     = (const float*)d_in[3];
  const float* U      = (const float*)d_in[4];
  const float* V      = (const float*)d_in[5];
  float* out = (float*)d_out;
  char* ws = (char*)d_ws;

  unsigned short* P   = (unsigned short*)ws;                   // 33,554,432 B
  unsigned short* hbf = (unsigned short*)ws;                   // dies before P written
  unsigned short* wbf = (unsigned short*)(ws + 16777216);      // dies before P written
  unsigned short* vlt = (unsigned short*)(ws + 33554432);      // 16,777,216 B
  float* aL   = (float*)(ws + 50331648);
  float* vArr = aL + 8192;

  prep_hidden<<<8192, 256, 0, stream>>>(hidden, U, V, hbf, aL, vArr);
  prep_w<<<1024, 256, 0, stream>>>(vw, wbf);
  gemm_vl<<<1024, 256, 0, stream>>>(hbf, wbf, vb, vlt);
  statsP<<<8192, 256, 0, stream>>>(aL, vArr, mask, P);
  attn<<<1024, 256, 0, stream>>>(P, vlt, out);
}

// Round 5
// 189.688 us; speedup vs baseline: 1.0162x; 1.0162x over previous
//
#include <hip/hip_runtime.h>
#include <hip/hip_bf16.h>
#include <stdint.h>

#define LOG2E 1.44269504088896340736f

typedef float f32x4 __attribute__((ext_vector_type(4)));
typedef __bf16 bf16x8 __attribute__((ext_vector_type(8)));

__device__ __forceinline__ void g2lds16(const void* g, void* l) {
  __builtin_amdgcn_global_load_lds(
      (__attribute__((address_space(1))) unsigned int*)g,
      (__attribute__((address_space(3))) unsigned int*)l,
      16, 0, 0);
}

__device__ __forceinline__ unsigned short f2bf_u(float f) {
  __bf16 h = (__bf16)f;
  return __builtin_bit_cast(unsigned short, h);
}

// ---------------------------------------------------------------------------
// prep_hidden: one block per row, XCD-colocated: pid -> row (pid&7)*1024 +
// (pid>>3), so XCD x (pid%8==x) writes hbf rows [x*1024,(x+1)*1024) -- the
// exact rows gemm_vl's XCD-x blocks read as A-tiles (L2 dirty-hit).
// Converts hidden row to bf16, computes xu/xv dots.
// ---------------------------------------------------------------------------
__global__ void __launch_bounds__(256) prep_hidden(
    const float* __restrict__ hidden, const float* __restrict__ U,
    const float* __restrict__ V, unsigned short* __restrict__ hbf,
    float* __restrict__ aL, float* __restrict__ vArr) {
  int pid = blockIdx.x;
  int row = ((pid & 7) << 10) | (pid >> 3);
  int tid = threadIdx.x;
  const float* hr = hidden + (size_t)row * 1024;
  float4 x = *(const float4*)&hr[tid * 4];
  float4 u = *(const float4*)&U[tid * 4];
  float4 v = *(const float4*)&V[tid * 4];
  ushort4 hb;
  hb.x = f2bf_u(x.x); hb.y = f2bf_u(x.y); hb.z = f2bf_u(x.z); hb.w = f2bf_u(x.w);
  *(ushort4*)&hbf[(size_t)row * 1024 + tid * 4] = hb;
  float su = x.x * u.x + x.y * u.y + x.z * u.z + x.w * u.w;
  float sv = x.x * v.x + x.y * v.y + x.z * v.z + x.w * v.w;
  for (int off = 32; off > 0; off >>= 1) {
    su += __shfl_down(su, off);
    sv += __shfl_down(sv, off);
  }
  __shared__ float red[8];
  int lane = tid & 63, w = tid >> 6;
  if (lane == 0) { red[w] = su; red[4 + w] = sv; }
  __syncthreads();
  if (tid == 0) {
    float xu = red[0] + red[1] + red[2] + red[3] + U[1024];
    float xv = red[4] + red[5] + red[6] + red[7] + V[1024];
    aL[row] = xu * 0.125f * LOG2E;
    vArr[row] = xv;
  }
}

// ---------------------------------------------------------------------------
__global__ void __launch_bounds__(256) prep_w(const float* __restrict__ w,
                                              unsigned short* __restrict__ wbf) {
  int idx = (blockIdx.x * 256 + threadIdx.x) * 4;
  float4 x = *(const float4*)&w[idx];
  ushort4 hb;
  hb.x = f2bf_u(x.x); hb.y = f2bf_u(x.y); hb.z = f2bf_u(x.z); hb.w = f2bf_u(x.w);
  *(ushort4*)&wbf[idx] = hb;
}

// ---------------------------------------------------------------------------
// statsP: XCD-colocated like prep_hidden: pid -> row (pid&7)*1024 + (pid>>3),
// so P rows land dirty in the L2 of the XCD whose attn blocks will read them.
// Mask fused (scaled by log2e inline). Writes P'[i][t] = invZ*exp2(...-mx).
// ---------------------------------------------------------------------------
__global__ void __launch_bounds__(256) statsP(
    const float* __restrict__ aL, const float* __restrict__ vArr,
    const float* __restrict__ mask, unsigned short* __restrict__ p) {
  int pid = blockIdx.x;
  int i = ((pid & 7) << 10) | (pid >> 3);
  int tb = (i >> 11) << 11;
  int tid = threadIdx.x;
  int t0 = tid * 8;
  float a = aL[i];
  float4 v0 = *(const float4*)&vArr[tb + t0];
  float4 v1 = *(const float4*)&vArr[tb + t0 + 4];
  float4 m0 = *(const float4*)&mask[tb + t0];
  float4 m1 = *(const float4*)&mask[tb + t0 + 4];
  float s[8];
  s[0] = fmaf(a, v0.x, m0.x * LOG2E); s[1] = fmaf(a, v0.y, m0.y * LOG2E);
  s[2] = fmaf(a, v0.z, m0.z * LOG2E); s[3] = fmaf(a, v0.w, m0.w * LOG2E);
  s[4] = fmaf(a, v1.x, m1.x * LOG2E); s[5] = fmaf(a, v1.y, m1.y * LOG2E);
  s[6] = fmaf(a, v1.z, m1.z * LOG2E); s[7] = fmaf(a, v1.w, m1.w * LOG2E);
  float mloc = s[0];
#pragma unroll
  for (int u = 1; u < 8; ++u) mloc = fmaxf(mloc, s[u]);
  for (int off = 32; off > 0; off >>= 1) mloc = fmaxf(mloc, __shfl_down(mloc, off));
  __shared__ float red[8];
  __shared__ float bc[2];
  int lane = tid & 63, w = tid >> 6;
  if (lane == 0) red[w] = mloc;
  __syncthreads();
  if (tid == 0) bc[0] = fmaxf(fmaxf(red[0], red[1]), fmaxf(red[2], red[3]));
  __syncthreads();
  float mx = bc[0];
  float pe[8];
  float z = 0.f;
#pragma unroll
  for (int u = 0; u < 8; ++u) {
    pe[u] = __builtin_amdgcn_exp2f(s[u] - mx);
    z += pe[u];
  }
  for (int off = 32; off > 0; off >>= 1) z += __shfl_down(z, off);
  if (lane == 0) red[4 + w] = z;
  __syncthreads();
  if (tid == 0) bc[1] = 1.0f / (red[4] + red[5] + red[6] + red[7]);
  __syncthreads();
  float iz = bc[1];
  bf16x8 o;
#pragma unroll
  for (int u = 0; u < 8; ++u) o[u] = (__bf16)(iz * pe[u]);
  *(bf16x8*)&p[(size_t)i * 2048 + t0] = o;
}

// ---------------------------------------------------------------------------
// gemm_vl: VL = hbf @ Wbf^T + bias, stored TRANSPOSED bf16: vlt[h][i],
// pitch 8192. M=8192 N=1024 K=1024. 128x128 tile, BK=32, 512 blocks.
// XCD swizzle: xcd = pid&7 -> m-tiles [xcd*8, xcd*8+8) x 8 n-tiles; hbf rows
// for those m-tiles are resident in this XCD's L2 (prep_hidden colocation).
// ---------------------------------------------------------------------------
__global__ void __launch_bounds__(256) gemm_vl(
    const unsigned short* __restrict__ hbf, const unsigned short* __restrict__ wbf,
    const float* __restrict__ bias, unsigned short* __restrict__ vlt) {
  __shared__ __align__(16) char sA[128 * 64];
  __shared__ __align__(16) char sB[128 * 64];
  int tid = threadIdx.x;
  int lane = tid & 63, wave = tid >> 6;
  int pid = blockIdx.x;
  int xcd = pid & 7, kk = pid >> 3;
  int m0 = (xcd * 8 + (kk >> 3)) * 128;
  int n0 = (kk & 7) * 128;
  int sr = lane >> 2, sc = lane & 3;
  int wr = wave >> 1, wc = wave & 1;
  int m_ = lane & 15, q = lane >> 4;
  int e = (m_ >> 1) & 3;
  const char* arp = sA + ((wr * 64 + m_) * 64) + ((q ^ e) * 16);
  const char* brp = sB + ((wc * 64 + m_) * 64) + ((q ^ e) * 16);
  f32x4 acc[4][4] = {};
  for (int k0 = 0; k0 < 1024; k0 += 32) {
    __syncthreads();
#pragma unroll
    for (int ii = 0; ii < 2; ++ii) {
      int r0 = wave * 32 + ii * 16;
      int r = r0 + sr;
      int cg = sc ^ ((r >> 1) & 3);
      g2lds16(hbf + ((size_t)(m0 + r) * 1024 + k0 + cg * 8), sA + r0 * 64);
      g2lds16(wbf + ((size_t)(n0 + r) * 1024 + k0 + cg * 8), sB + r0 * 64);
    }
    __syncthreads();
    bf16x8 af[4], bfr[4];
#pragma unroll
    for (int i = 0; i < 4; ++i) af[i] = *(const bf16x8*)(arp + i * 1024);
#pragma unroll
    for (int j = 0; j < 4; ++j) bfr[j] = *(const bf16x8*)(brp + j * 1024);
#pragma unroll
    for (int i = 0; i < 4; ++i)
#pragma unroll
      for (int j = 0; j < 4; ++j)
        acc[i][j] = __builtin_amdgcn_mfma_f32_16x16x32_bf16(af[i], bfr[j], acc[i][j], 0, 0, 0);
  }
#pragma unroll
  for (int jt = 0; jt < 4; ++jt) {
    int j = n0 + wc * 64 + jt * 16 + m_;
    float bj = bias[j];
#pragma unroll
    for (int it = 0; it < 4; ++it) {
      int i = m0 + wr * 64 + it * 16 + q * 4;
      f32x4 a = acc[it][jt];
      ushort4 o;
      o.x = f2bf_u(a.x + bj); o.y = f2bf_u(a.y + bj);
      o.z = f2bf_u(a.z + bj); o.w = f2bf_u(a.w + bj);
      *(ushort4*)&vlt[(size_t)j * 8192 + i] = o;
    }
  }
}

// ---------------------------------------------------------------------------
// attn: C = P' @ VL^T-slice, full K=2048 (invZ folded into P'). 512 blocks,
// 128x128 tile, BK=32. XCD swizzle: xcd = pid&7 -> s-tiles [xcd*8, xcd*8+8)
// x 8 h-tiles. P rows AND vlt cols for this range are L2-resident on this
// XCD (statsP / gemm_vl colocation).
// ---------------------------------------------------------------------------
__global__ void __launch_bounds__(256) attn(
    const unsigned short* __restrict__ p, const unsigned short* __restrict__ vlt,
    float* __restrict__ out) {
  __shared__ __align__(16) char sA[128 * 64];
  __shared__ __align__(16) char sB[128 * 64];
  int tid = threadIdx.x;
  int lane = tid & 63, wave = tid >> 6;
  int pid = blockIdx.x;
  int xcd = pid & 7, kk = pid >> 3;
  int i0 = (xcd * 8 + (kk >> 3)) * 128;  // s-row tile (batch-major)
  int h0 = (kk & 7) * 128;               // h tile
  int b = i0 >> 11;
  size_t toff = (size_t)b << 11;
  int sr = lane >> 2, sc = lane & 3;
  int wr = wave >> 1, wc = wave & 1;
  int m_ = lane & 15, q = lane >> 4;
  int e = (m_ >> 1) & 3;
  const char* arp = sA + ((wr * 64 + m_) * 64) + ((q ^ e) * 16);
  const char* brp = sB + ((wc * 64 + m_) * 64) + ((q ^ e) * 16);
  f32x4 acc[4][4] = {};
  for (int k0 = 0; k0 < 2048; k0 += 32) {
    __syncthreads();
#pragma unroll
    for (int ii = 0; ii < 2; ++ii) {
      int r0 = wave * 32 + ii * 16;
      int r = r0 + sr;
      int cg = sc ^ ((r >> 1) & 3);
      g2lds16(p + ((size_t)(i0 + r) * 2048 + k0 + cg * 8), sA + r0 * 64);
      g2lds16(vlt + ((size_t)(h0 + r) * 8192 + toff + k0 + cg * 8), sB + r0 * 64);
    }
    __syncthreads();
    bf16x8 af[4], bfr[4];
#pragma unroll
    for (int i = 0; i < 4; ++i) af[i] = *(const bf16x8*)(arp + i * 1024);
#pragma unroll
    for (int j = 0; j < 4; ++j) bfr[j] = *(const bf16x8*)(brp + j * 1024);
#pragma unroll
    for (int i = 0; i < 4; ++i)
#pragma unroll
      for (int j = 0; j < 4; ++j)
        acc[i][j] = __builtin_amdgcn_mfma_f32_16x16x32_bf16(af[i], bfr[j], acc[i][j], 0, 0, 0);
  }
#pragma unroll
  for (int it = 0; it < 4; ++it) {
    int gi = i0 + wr * 64 + it * 16 + q * 4;
#pragma unroll
    for (int jt = 0; jt < 4; ++jt) {
      int h = h0 + wc * 64 + jt * 16 + m_;
      f32x4 a = acc[it][jt];
      out[(size_t)(gi + 0) * 1024 + h] = a.x;
      out[(size_t)(gi + 1) * 1024 + h] = a.y;
      out[(size_t)(gi + 2) * 1024 + h] = a.z;
      out[(size_t)(gi + 3) * 1024 + h] = a.w;
    }
  }
}

// ---------------------------------------------------------------------------
// ws layout (peak ~50.4 MB):
//   [0, 33.5MB)        P' (bf16) -- overlaps hbf[0,16MB)+wbf[16,18MB), which
//                                   die after gemm_vl; statsP runs after.
//   [33.5MB, 50.3MB)   vlt (bf16, [1024][8192])
//   [50.3MB, 50.4MB)   aL, vArr (2 x 32KB fp32)
// ---------------------------------------------------------------------------
extern "C" void kernel_launch(void* const* d_in, const int* in_sizes, int n_in,
                              void* d_out, int out_size, void* d_ws, size_t ws_size,
                              hipStream_t stream) {
  const float* hidden = (const float*)d_in[0];
  const float* mask   = (const float*)d_in[1];
  const float* vw     = (const float*)d_in[2];
  const float* vb     = (const float*)d_in[3];
  const float* U      = (const float*)d_in[4];
  const float* V      = (const float*)d_in[5];
  float* out = (float*)d_out;
  char* ws = (char*)d_ws;

  unsigned short* P   = (unsigned short*)ws;                   // 33,554,432 B
  unsigned short* hbf = (unsigned short*)ws;                   // dies before P written
  unsigned short* wbf = (unsigned short*)(ws + 16777216);      // dies before P written
  unsigned short* vlt = (unsigned short*)(ws + 33554432);      // 16,777,216 B
  float* aL   = (float*)(ws + 50331648);
  float* vArr = aL + 8192;

  prep_hidden<<<8192, 256, 0, stream>>>(hidden, U, V, hbf, aL, vArr);
  prep_w<<<1024, 256, 0, stream>>>(vw, wbf);
  gemm_vl<<<512, 256, 0, stream>>>(hbf, wbf, vb, vlt);
  statsP<<<8192, 256, 0, stream>>>(aL, vArr, mask, P);
  attn<<<512, 256, 0, stream>>>(P, vlt, out);
}

// Round 6
// 188.553 us; speedup vs baseline: 1.0223x; 1.0060x over previous
//
#include <hip/hip_runtime.h>
#include <hip/hip_bf16.h>
#include <stdint.h>

#define LOG2E 1.44269504088896340736f

typedef float f32x4 __attribute__((ext_vector_type(4)));
typedef __bf16 bf16x8 __attribute__((ext_vector_type(8)));

__device__ __forceinline__ void g2lds16(const void* g, void* l) {
  __builtin_amdgcn_global_load_lds(
      (__attribute__((address_space(1))) unsigned int*)g,
      (__attribute__((address_space(3))) unsigned int*)l,
      16, 0, 0);
}

__device__ __forceinline__ unsigned short f2bf_u(float f) {
  __bf16 h = (__bf16)f;
  return __builtin_bit_cast(unsigned short, h);
}

// ---------------------------------------------------------------------------
// prep_hidden: barrier-free. 512 blocks x 4 waves; each wave owns 4 rows.
// U/V fragments register-cached once per wave. Dots reduced with xor-butterfly
// shuffles (no LDS, no __syncthreads). XCD-colocated: block b (XCD b&7)
// writes hbf rows [xcd*1024, ...) that gemm_vl's XCD-b&7 blocks read.
// Element ownership: lane l, chunk c -> elems c*256 + l*4 .. +3 (coalesced).
// ---------------------------------------------------------------------------
__global__ void __launch_bounds__(256) prep_hidden(
    const float* __restrict__ hidden, const float* __restrict__ U,
    const float* __restrict__ V, unsigned short* __restrict__ hbf,
    float* __restrict__ aL, float* __restrict__ vArr) {
  int tid = threadIdx.x;
  int lane = tid & 63, w = tid >> 6;
  int b = blockIdx.x;
  int xcd = b & 7, idx = b >> 3;          // idx in [0,64)
  int row0 = (xcd << 10) + (idx * 4 + w) * 4;  // 4 rows per wave
  float4 u4[4], v4[4];
#pragma unroll
  for (int c = 0; c < 4; ++c) {
    u4[c] = *(const float4*)&U[c * 256 + lane * 4];
    v4[c] = *(const float4*)&V[c * 256 + lane * 4];
  }
  float u_t = U[1024], v_t = V[1024];
  float su[4], sv[4];
#pragma unroll
  for (int r = 0; r < 4; ++r) {
    const float* hr = hidden + (size_t)(row0 + r) * 1024;
    unsigned short* hb = hbf + (size_t)(row0 + r) * 1024;
    float ssu = 0.f, ssv = 0.f;
#pragma unroll
    for (int c = 0; c < 4; ++c) {
      float4 x = *(const float4*)&hr[c * 256 + lane * 4];
      ushort4 o;
      o.x = f2bf_u(x.x); o.y = f2bf_u(x.y); o.z = f2bf_u(x.z); o.w = f2bf_u(x.w);
      *(ushort4*)&hb[c * 256 + lane * 4] = o;
      ssu += x.x * u4[c].x + x.y * u4[c].y + x.z * u4[c].z + x.w * u4[c].w;
      ssv += x.x * v4[c].x + x.y * v4[c].y + x.z * v4[c].z + x.w * v4[c].w;
    }
    su[r] = ssu; sv[r] = ssv;
  }
#pragma unroll
  for (int off = 1; off < 64; off <<= 1) {
#pragma unroll
    for (int r = 0; r < 4; ++r) {
      su[r] += __shfl_xor(su[r], off);
      sv[r] += __shfl_xor(sv[r], off);
    }
  }
  if (lane < 4) {
    int r = lane;
    float sur = (r == 0) ? su[0] : (r == 1) ? su[1] : (r == 2) ? su[2] : su[3];
    float svr = (r == 0) ? sv[0] : (r == 1) ? sv[1] : (r == 2) ? sv[2] : sv[3];
    aL[row0 + r] = (sur + u_t) * 0.125f * LOG2E;
    vArr[row0 + r] = svr + v_t;
  }
}

// ---------------------------------------------------------------------------
__global__ void __launch_bounds__(256) prep_w(const float* __restrict__ w,
                                              unsigned short* __restrict__ wbf) {
  int idx = (blockIdx.x * 256 + threadIdx.x) * 4;
  float4 x = *(const float4*)&w[idx];
  ushort4 hb;
  hb.x = f2bf_u(x.x); hb.y = f2bf_u(x.y); hb.z = f2bf_u(x.z); hb.w = f2bf_u(x.w);
  *(ushort4*)&wbf[idx] = hb;
}

// ---------------------------------------------------------------------------
// statsP: barrier-free. 256 blocks x 4 waves; each wave owns 8 consecutive
// rows (same batch). vArr/mask (32 elems/lane) register-cached once per wave
// and reused across the 8 rows. Per row: max + sum via xor-butterfly (no LDS,
// no __syncthreads), then P'[i][t] = invZ*exp2(aL*v + mask*log2e - mx) as 4
// coalesced bf16x8 stores. XCD-colocated mapping (pid&7 = writer XCD).
// Lane l, chunk c owns t = c*512 + l*8 .. +7.
// ---------------------------------------------------------------------------
__global__ void __launch_bounds__(256) statsP(
    const float* __restrict__ aL, const float* __restrict__ vArr,
    const float* __restrict__ mask, unsigned short* __restrict__ p) {
  int tid = threadIdx.x;
  int lane = tid & 63, w = tid >> 6;
  int b = blockIdx.x;
  int xcd = b & 7, idx = b >> 3;          // idx in [0,32)
  int row0 = (xcd << 10) + (idx * 4 + w) * 8;  // 8 rows per wave
  int tb = (row0 >> 11) << 11;
  float4 va[8], ma[8];
#pragma unroll
  for (int c = 0; c < 4; ++c) {
    int t = c * 512 + lane * 8;
    va[2 * c]     = *(const float4*)&vArr[tb + t];
    va[2 * c + 1] = *(const float4*)&vArr[tb + t + 4];
    float4 m0 = *(const float4*)&mask[tb + t];
    float4 m1 = *(const float4*)&mask[tb + t + 4];
    ma[2 * c].x = m0.x * LOG2E; ma[2 * c].y = m0.y * LOG2E;
    ma[2 * c].z = m0.z * LOG2E; ma[2 * c].w = m0.w * LOG2E;
    ma[2 * c + 1].x = m1.x * LOG2E; ma[2 * c + 1].y = m1.y * LOG2E;
    ma[2 * c + 1].z = m1.z * LOG2E; ma[2 * c + 1].w = m1.w * LOG2E;
  }
#pragma unroll
  for (int r = 0; r < 8; ++r) {
    int row = row0 + r;
    float a = aL[row];
    float s[32];
#pragma unroll
    for (int q = 0; q < 8; ++q) {
      s[q * 4 + 0] = fmaf(a, va[q].x, ma[q].x);
      s[q * 4 + 1] = fmaf(a, va[q].y, ma[q].y);
      s[q * 4 + 2] = fmaf(a, va[q].z, ma[q].z);
      s[q * 4 + 3] = fmaf(a, va[q].w, ma[q].w);
    }
    float mx = s[0];
#pragma unroll
    for (int u = 1; u < 32; ++u) mx = fmaxf(mx, s[u]);
#pragma unroll
    for (int off = 1; off < 64; off <<= 1) mx = fmaxf(mx, __shfl_xor(mx, off));
    float z = 0.f;
#pragma unroll
    for (int u = 0; u < 32; ++u) {
      s[u] = __builtin_amdgcn_exp2f(s[u] - mx);
      z += s[u];
    }
#pragma unroll
    for (int off = 1; off < 64; off <<= 1) z += __shfl_xor(z, off);
    float iz = __builtin_amdgcn_rcpf(z);
    unsigned short* pr = p + (size_t)row * 2048;
#pragma unroll
    for (int c = 0; c < 4; ++c) {
      bf16x8 o;
#pragma unroll
      for (int u = 0; u < 8; ++u) o[u] = (__bf16)(iz * s[c * 8 + u]);
      *(bf16x8*)&pr[c * 512 + lane * 8] = o;
    }
  }
}

// ---------------------------------------------------------------------------
// gemm_vl: VL = hbf @ Wbf^T + bias, stored TRANSPOSED bf16: vlt[h][i],
// pitch 8192. M=8192 N=1024 K=1024. 128x128 tile, BK=32, 512 blocks.
// XCD swizzle: xcd = pid&7 -> m-tiles [xcd*8, xcd*8+8) x 8 n-tiles; hbf rows
// for those m-tiles are resident in this XCD's L2 (prep_hidden colocation).
// ---------------------------------------------------------------------------
__global__ void __launch_bounds__(256) gemm_vl(
    const unsigned short* __restrict__ hbf, const unsigned short* __restrict__ wbf,
    const float* __restrict__ bias, unsigned short* __restrict__ vlt) {
  __shared__ __align__(16) char sA[128 * 64];
  __shared__ __align__(16) char sB[128 * 64];
  int tid = threadIdx.x;
  int lane = tid & 63, wave = tid >> 6;
  int pid = blockIdx.x;
  int xcd = pid & 7, kk = pid >> 3;
  int m0 = (xcd * 8 + (kk >> 3)) * 128;
  int n0 = (kk & 7) * 128;
  int sr = lane >> 2, sc = lane & 3;
  int wr = wave >> 1, wc = wave & 1;
  int m_ = lane & 15, q = lane >> 4;
  int e = (m_ >> 1) & 3;
  const char* arp = sA + ((wr * 64 + m_) * 64) + ((q ^ e) * 16);
  const char* brp = sB + ((wc * 64 + m_) * 64) + ((q ^ e) * 16);
  f32x4 acc[4][4] = {};
  for (int k0 = 0; k0 < 1024; k0 += 32) {
    __syncthreads();
#pragma unroll
    for (int ii = 0; ii < 2; ++ii) {
      int r0 = wave * 32 + ii * 16;
      int r = r0 + sr;
      int cg = sc ^ ((r >> 1) & 3);
      g2lds16(hbf + ((size_t)(m0 + r) * 1024 + k0 + cg * 8), sA + r0 * 64);
      g2lds16(wbf + ((size_t)(n0 + r) * 1024 + k0 + cg * 8), sB + r0 * 64);
    }
    __syncthreads();
    bf16x8 af[4], bfr[4];
#pragma unroll
    for (int i = 0; i < 4; ++i) af[i] = *(const bf16x8*)(arp + i * 1024);
#pragma unroll
    for (int j = 0; j < 4; ++j) bfr[j] = *(const bf16x8*)(brp + j * 1024);
#pragma unroll
    for (int i = 0; i < 4; ++i)
#pragma unroll
      for (int j = 0; j < 4; ++j)
        acc[i][j] = __builtin_amdgcn_mfma_f32_16x16x32_bf16(af[i], bfr[j], acc[i][j], 0, 0, 0);
  }
#pragma unroll
  for (int jt = 0; jt < 4; ++jt) {
    int j = n0 + wc * 64 + jt * 16 + m_;
    float bj = bias[j];
#pragma unroll
    for (int it = 0; it < 4; ++it) {
      int i = m0 + wr * 64 + it * 16 + q * 4;
      f32x4 a = acc[it][jt];
      ushort4 o;
      o.x = f2bf_u(a.x + bj); o.y = f2bf_u(a.y + bj);
      o.z = f2bf_u(a.z + bj); o.w = f2bf_u(a.w + bj);
      *(ushort4*)&vlt[(size_t)j * 8192 + i] = o;
    }
  }
}

// ---------------------------------------------------------------------------
// attn: C = P' @ VL^T-slice, full K=2048 (invZ folded into P'). 512 blocks,
// 128x128 tile, BK=32. XCD swizzle: xcd = pid&7 -> s-tiles [xcd*8, xcd*8+8)
// x 8 h-tiles.
// ---------------------------------------------------------------------------
__global__ void __launch_bounds__(256) attn(
    const unsigned short* __restrict__ p, const unsigned short* __restrict__ vlt,
    float* __restrict__ out) {
  __shared__ __align__(16) char sA[128 * 64];
  __shared__ __align__(16) char sB[128 * 64];
  int tid = threadIdx.x;
  int lane = tid & 63, wave = tid >> 6;
  int pid = blockIdx.x;
  int xcd = pid & 7, kk = pid >> 3;
  int i0 = (xcd * 8 + (kk >> 3)) * 128;  // s-row tile (batch-major)
  int h0 = (kk & 7) * 128;               // h tile
  int b = i0 >> 11;
  size_t toff = (size_t)b << 11;
  int sr = lane >> 2, sc = lane & 3;
  int wr = wave >> 1, wc = wave & 1;
  int m_ = lane & 15, q = lane >> 4;
  int e = (m_ >> 1) & 3;
  const char* arp = sA + ((wr * 64 + m_) * 64) + ((q ^ e) * 16);
  const char* brp = sB + ((wc * 64 + m_) * 64) + ((q ^ e) * 16);
  f32x4 acc[4][4] = {};
  for (int k0 = 0; k0 < 2048; k0 += 32) {
    __syncthreads();
#pragma unroll
    for (int ii = 0; ii < 2; ++ii) {
      int r0 = wave * 32 + ii * 16;
      int r = r0 + sr;
      int cg = sc ^ ((r >> 1) & 3);
      g2lds16(p + ((size_t)(i0 + r) * 2048 + k0 + cg * 8), sA + r0 * 64);
      g2lds16(vlt + ((size_t)(h0 + r) * 8192 + toff + k0 + cg * 8), sB + r0 * 64);
    }
    __syncthreads();
    bf16x8 af[4], bfr[4];
#pragma unroll
    for (int i = 0; i < 4; ++i) af[i] = *(const bf16x8*)(arp + i * 1024);
#pragma unroll
    for (int j = 0; j < 4; ++j) bfr[j] = *(const bf16x8*)(brp + j * 1024);
#pragma unroll
    for (int i = 0; i < 4; ++i)
#pragma unroll
      for (int j = 0; j < 4; ++j)
        acc[i][j] = __builtin_amdgcn_mfma_f32_16x16x32_bf16(af[i], bfr[j], acc[i][j], 0, 0, 0);
  }
#pragma unroll
  for (int it = 0; it < 4; ++it) {
    int gi = i0 + wr * 64 + it * 16 + q * 4;
#pragma unroll
    for (int jt = 0; jt < 4; ++jt) {
      int h = h0 + wc * 64 + jt * 16 + m_;
      f32x4 a = acc[it][jt];
      out[(size_t)(gi + 0) * 1024 + h] = a.x;
      out[(size_t)(gi + 1) * 1024 + h] = a.y;
      out[(size_t)(gi + 2) * 1024 + h] = a.z;
      out[(size_t)(gi + 3) * 1024 + h] = a.w;
    }
  }
}

// ---------------------------------------------------------------------------
// ws layout (peak ~50.4 MB):
//   [0, 33.5MB)        P' (bf16) -- overlaps hbf[0,16MB)+wbf[16,18MB), which
//                                   die after gemm_vl; statsP runs after.
//   [33.5MB, 50.3MB)   vlt (bf16, [1024][8192])
//   [50.3MB, 50.4MB)   aL, vArr (2 x 32KB fp32)
// ---------------------------------------------------------------------------
extern "C" void kernel_launch(void* const* d_in, const int* in_sizes, int n_in,
                              void* d_out, int out_size, void* d_ws, size_t ws_size,
                              hipStream_t stream) {
  const float* hidden = (const float*)d_in[0];
  const float* mask   = (const float*)d_in[1];
  const float* vw     = (const float*)d_in[2];
  const float* vb     = (const float*)d_in[3];
  const float* U      = (const float*)d_in[4];
  const float* V      = (const float*)d_in[5];
  float* out = (float*)d_out;
  char* ws = (char*)d_ws;

  unsigned short* P   = (unsigned short*)ws;                   // 33,554,432 B
  unsigned short* hbf = (unsigned short*)ws;                   // dies before P written
  unsigned short* wbf = (unsigned short*)(ws + 16777216);      // dies before P written
  unsigned short* vlt = (unsigned short*)(ws + 33554432);      // 16,777,216 B
  float* aL   = (float*)(ws + 50331648);
  float* vArr = aL + 8192;

  prep_hidden<<<512, 256, 0, stream>>>(hidden, U, V, hbf, aL, vArr);
  prep_w<<<1024, 256, 0, stream>>>(vw, wbf);
  gemm_vl<<<512, 256, 0, stream>>>(hbf, wbf, vb, vlt);
  statsP<<<256, 256, 0, stream>>>(aL, vArr, mask, P);
  attn<<<512, 256, 0, stream>>>(P, vlt, out);
}

// Round 7
// 168.584 us; speedup vs baseline: 1.1434x; 1.1185x over previous
//
#include <hip/hip_runtime.h>
#include <hip/hip_bf16.h>
#include <stdint.h>

#define LOG2E 1.44269504088896340736f

typedef float f32x4 __attribute__((ext_vector_type(4)));
typedef __bf16 bf16x8 __attribute__((ext_vector_type(8)));

__device__ __forceinline__ void g2lds16(const void* g, void* l) {
  __builtin_amdgcn_global_load_lds(
      (__attribute__((address_space(1))) unsigned int*)g,
      (__attribute__((address_space(3))) unsigned int*)l,
      16, 0, 0);
}

__device__ __forceinline__ unsigned short f2bf_u(float f) {
  __bf16 h = (__bf16)f;
  return __builtin_bit_cast(unsigned short, h);
}

// ---------------------------------------------------------------------------
// fused_prep: 640 blocks. pid<512: prep_hidden (barrier-free, 4 waves x 4
// rows, XCD-colocated row mapping). pid>=512: prep_w grid-stride bf16 cast.
// ---------------------------------------------------------------------------
__global__ void __launch_bounds__(256) fused_prep(
    const float* __restrict__ hidden, const float* __restrict__ U,
    const float* __restrict__ V, const float* __restrict__ vw,
    unsigned short* __restrict__ hbf, unsigned short* __restrict__ wbf,
    float* __restrict__ aL, float* __restrict__ vArr) {
  int tid = threadIdx.x;
  int pid = blockIdx.x;
  if (pid < 512) {
    int lane = tid & 63, w = tid >> 6;
    int xcd = pid & 7, idx = pid >> 3;
    int row0 = (xcd << 10) + (idx * 4 + w) * 4;
    float4 u4[4], v4[4];
#pragma unroll
    for (int c = 0; c < 4; ++c) {
      u4[c] = *(const float4*)&U[c * 256 + lane * 4];
      v4[c] = *(const float4*)&V[c * 256 + lane * 4];
    }
    float u_t = U[1024], v_t = V[1024];
    float su[4], sv[4];
#pragma unroll
    for (int r = 0; r < 4; ++r) {
      const float* hr = hidden + (size_t)(row0 + r) * 1024;
      unsigned short* hb = hbf + (size_t)(row0 + r) * 1024;
      float ssu = 0.f, ssv = 0.f;
#pragma unroll
      for (int c = 0; c < 4; ++c) {
        float4 x = *(const float4*)&hr[c * 256 + lane * 4];
        ushort4 o;
        o.x = f2bf_u(x.x); o.y = f2bf_u(x.y); o.z = f2bf_u(x.z); o.w = f2bf_u(x.w);
        *(ushort4*)&hb[c * 256 + lane * 4] = o;
        ssu += x.x * u4[c].x + x.y * u4[c].y + x.z * u4[c].z + x.w * u4[c].w;
        ssv += x.x * v4[c].x + x.y * v4[c].y + x.z * v4[c].z + x.w * v4[c].w;
      }
      su[r] = ssu; sv[r] = ssv;
    }
#pragma unroll
    for (int off = 1; off < 64; off <<= 1) {
#pragma unroll
      for (int r = 0; r < 4; ++r) {
        su[r] += __shfl_xor(su[r], off);
        sv[r] += __shfl_xor(sv[r], off);
      }
    }
    if (lane < 4) {
      int r = lane;
      float sur = (r == 0) ? su[0] : (r == 1) ? su[1] : (r == 2) ? su[2] : su[3];
      float svr = (r == 0) ? sv[0] : (r == 1) ? sv[1] : (r == 2) ? sv[2] : sv[3];
      aL[row0 + r] = (sur + u_t) * 0.125f * LOG2E;
      vArr[row0 + r] = svr + v_t;
    }
  } else {
    int wp = pid - 512;  // [0,128)
#pragma unroll
    for (int it = 0; it < 8; ++it) {
      int idx = (wp * 256 + tid) * 4 + it * 131072;
      float4 x = *(const float4*)&vw[idx];
      ushort4 o;
      o.x = f2bf_u(x.x); o.y = f2bf_u(x.y); o.z = f2bf_u(x.z); o.w = f2bf_u(x.w);
      *(ushort4*)&wbf[idx] = o;
    }
  }
}

// ---------------------------------------------------------------------------
// gemm_stats: pid < gemmBlocks -> gemm_vl (128x128 tile, BK=64, XCD swizzle);
// else -> statsP block (pid - gemmBlocks), barrier-free, 4 waves x 8 rows.
// With gemmBlocks=512 and grid=768 the stats blocks run concurrently on CUs
// freed by finished gemm blocks (requires P disjoint from hbf/wbf!).
// With gemmBlocks=0 it is a pure statsP launch (fallback layout).
// BK=64 swizzle: physical chunk = global chunk ^ (row&7); staging satisfies
// global_load_lds's (wave-uniform base + lane*16) constraint by construction.
// ---------------------------------------------------------------------------
__global__ void __launch_bounds__(256) gemm_stats(
    const unsigned short* __restrict__ hbf, const unsigned short* __restrict__ wbf,
    const float* __restrict__ bias, unsigned short* __restrict__ vlt,
    const float* __restrict__ aL, const float* __restrict__ vArr,
    const float* __restrict__ mask, unsigned short* __restrict__ P,
    int gemmBlocks) {
  __shared__ __align__(16) char sA[128 * 128];
  __shared__ __align__(16) char sB[128 * 128];
  int tid = threadIdx.x;
  int pid = blockIdx.x;
  if (pid < gemmBlocks) {
    int lane = tid & 63, wave = tid >> 6;
    int xcd = pid & 7, kk = pid >> 3;
    int m0 = (xcd * 8 + (kk >> 3)) * 128;
    int n0 = (kk & 7) * 128;
    int srow = lane >> 3;          // 0..7
    int sgc = (lane & 7) ^ srow;   // global chunk to fetch
    int wr = wave >> 1, wc = wave & 1;
    int m_ = lane & 15, q = lane >> 4;
    int e8 = m_ & 7;
    f32x4 acc[4][4] = {};
    for (int k0 = 0; k0 < 1024; k0 += 64) {
      __syncthreads();
#pragma unroll
      for (int ii = 0; ii < 4; ++ii) {
        int rb = ii * 32 + wave * 8;
        int r = rb + srow;
        g2lds16(hbf + (size_t)(m0 + r) * 1024 + k0 + sgc * 8, sA + rb * 128);
        g2lds16(wbf + (size_t)(n0 + r) * 1024 + k0 + sgc * 8, sB + rb * 128);
      }
      __syncthreads();
#pragma unroll
      for (int ks = 0; ks < 2; ++ks) {
        bf16x8 af[4], bfr[4];
#pragma unroll
        for (int i = 0; i < 4; ++i)
          af[i] = *(const bf16x8*)(sA + (wr * 64 + i * 16 + m_) * 128 + (((q + 4 * ks) ^ e8) * 16));
#pragma unroll
        for (int j = 0; j < 4; ++j)
          bfr[j] = *(const bf16x8*)(sB + (wc * 64 + j * 16 + m_) * 128 + (((q + 4 * ks) ^ e8) * 16));
#pragma unroll
        for (int i = 0; i < 4; ++i)
#pragma unroll
          for (int j = 0; j < 4; ++j)
            acc[i][j] = __builtin_amdgcn_mfma_f32_16x16x32_bf16(af[i], bfr[j], acc[i][j], 0, 0, 0);
      }
    }
#pragma unroll
    for (int jt = 0; jt < 4; ++jt) {
      int j = n0 + wc * 64 + jt * 16 + m_;
      float bj = bias[j];
#pragma unroll
      for (int it = 0; it < 4; ++it) {
        int i = m0 + wr * 64 + it * 16 + q * 4;
        f32x4 a = acc[it][jt];
        ushort4 o;
        o.x = f2bf_u(a.x + bj); o.y = f2bf_u(a.y + bj);
        o.z = f2bf_u(a.z + bj); o.w = f2bf_u(a.w + bj);
        *(ushort4*)&vlt[(size_t)j * 8192 + i] = o;
      }
    }
  } else {
    // ---- statsP path: barrier-free, wave-owned rows ----
    int b = pid - gemmBlocks;
    int lane = tid & 63, w = tid >> 6;
    int xcd = b & 7, idx = b >> 3;             // idx in [0,32)
    int row0 = (xcd << 10) + (idx * 4 + w) * 8;  // 8 rows per wave
    int tb = (row0 >> 11) << 11;
    float4 va[8], ma[8];
#pragma unroll
    for (int c = 0; c < 4; ++c) {
      int t = c * 512 + lane * 8;
      va[2 * c]     = *(const float4*)&vArr[tb + t];
      va[2 * c + 1] = *(const float4*)&vArr[tb + t + 4];
      float4 m0v = *(const float4*)&mask[tb + t];
      float4 m1v = *(const float4*)&mask[tb + t + 4];
      ma[2 * c].x = m0v.x * LOG2E; ma[2 * c].y = m0v.y * LOG2E;
      ma[2 * c].z = m0v.z * LOG2E; ma[2 * c].w = m0v.w * LOG2E;
      ma[2 * c + 1].x = m1v.x * LOG2E; ma[2 * c + 1].y = m1v.y * LOG2E;
      ma[2 * c + 1].z = m1v.z * LOG2E; ma[2 * c + 1].w = m1v.w * LOG2E;
    }
#pragma unroll
    for (int r = 0; r < 8; ++r) {
      int row = row0 + r;
      float a = aL[row];
      float s[32];
#pragma unroll
      for (int qq = 0; qq < 8; ++qq) {
        s[qq * 4 + 0] = fmaf(a, va[qq].x, ma[qq].x);
        s[qq * 4 + 1] = fmaf(a, va[qq].y, ma[qq].y);
        s[qq * 4 + 2] = fmaf(a, va[qq].z, ma[qq].z);
        s[qq * 4 + 3] = fmaf(a, va[qq].w, ma[qq].w);
      }
      float mx = s[0];
#pragma unroll
      for (int u = 1; u < 32; ++u) mx = fmaxf(mx, s[u]);
#pragma unroll
      for (int off = 1; off < 64; off <<= 1) mx = fmaxf(mx, __shfl_xor(mx, off));
      float z = 0.f;
#pragma unroll
      for (int u = 0; u < 32; ++u) {
        s[u] = __builtin_amdgcn_exp2f(s[u] - mx);
        z += s[u];
      }
#pragma unroll
      for (int off = 1; off < 64; off <<= 1) z += __shfl_xor(z, off);
      float iz = __builtin_amdgcn_rcpf(z);
      unsigned short* pr = P + (size_t)row * 2048;
#pragma unroll
      for (int c = 0; c < 4; ++c) {
        bf16x8 o;
#pragma unroll
        for (int u = 0; u < 8; ++u) o[u] = (__bf16)(iz * s[c * 8 + u]);
        *(bf16x8*)&pr[c * 512 + lane * 8] = o;
      }
    }
  }
}

// ---------------------------------------------------------------------------
// attn: C = P' @ VL^T-slice, full K=2048, BK=64 (32 barrier pairs instead of
// 64). 512 blocks, 128x128 tile. XCD swizzle as before.
// ---------------------------------------------------------------------------
__global__ void __launch_bounds__(256) attn(
    const unsigned short* __restrict__ p, const unsigned short* __restrict__ vlt,
    float* __restrict__ out) {
  __shared__ __align__(16) char sA[128 * 128];
  __shared__ __align__(16) char sB[128 * 128];
  int tid = threadIdx.x;
  int lane = tid & 63, wave = tid >> 6;
  int pid = blockIdx.x;
  int xcd = pid & 7, kk = pid >> 3;
  int i0 = (xcd * 8 + (kk >> 3)) * 128;  // s-row tile (batch-major)
  int h0 = (kk & 7) * 128;               // h tile
  int b = i0 >> 11;
  size_t toff = (size_t)b << 11;
  int srow = lane >> 3;
  int sgc = (lane & 7) ^ srow;
  int wr = wave >> 1, wc = wave & 1;
  int m_ = lane & 15, q = lane >> 4;
  int e8 = m_ & 7;
  f32x4 acc[4][4] = {};
  for (int k0 = 0; k0 < 2048; k0 += 64) {
    __syncthreads();
#pragma unroll
    for (int ii = 0; ii < 4; ++ii) {
      int rb = ii * 32 + wave * 8;
      int r = rb + srow;
      g2lds16(p + (size_t)(i0 + r) * 2048 + k0 + sgc * 8, sA + rb * 128);
      g2lds16(vlt + (size_t)(h0 + r) * 8192 + toff + k0 + sgc * 8, sB + rb * 128);
    }
    __syncthreads();
#pragma unroll
    for (int ks = 0; ks < 2; ++ks) {
      bf16x8 af[4], bfr[4];
#pragma unroll
      for (int i = 0; i < 4; ++i)
        af[i] = *(const bf16x8*)(sA + (wr * 64 + i * 16 + m_) * 128 + (((q + 4 * ks) ^ e8) * 16));
#pragma unroll
      for (int j = 0; j < 4; ++j)
        bfr[j] = *(const bf16x8*)(sB + (wc * 64 + j * 16 + m_) * 128 + (((q + 4 * ks) ^ e8) * 16));
#pragma unroll
      for (int i = 0; i < 4; ++i)
#pragma unroll
        for (int j = 0; j < 4; ++j)
          acc[i][j] = __builtin_amdgcn_mfma_f32_16x16x32_bf16(af[i], bfr[j], acc[i][j], 0, 0, 0);
    }
  }
#pragma unroll
  for (int it = 0; it < 4; ++it) {
    int gi = i0 + wr * 64 + it * 16 + q * 4;
#pragma unroll
    for (int jt = 0; jt < 4; ++jt) {
      int h = h0 + wc * 64 + jt * 16 + m_;
      f32x4 a = acc[it][jt];
      out[(size_t)(gi + 0) * 1024 + h] = a.x;
      out[(size_t)(gi + 1) * 1024 + h] = a.y;
      out[(size_t)(gi + 2) * 1024 + h] = a.z;
      out[(size_t)(gi + 3) * 1024 + h] = a.w;
    }
  }
}

// ---------------------------------------------------------------------------
// Layout A (ws >= 69.3 MB, 3 launches; P disjoint so statsP overlaps gemm):
//   hbf 0..16MB | wbf 16..18MB | vlt 18..34.8MB | P 34.8..68.3MB | aL,vArr
// Layout B (fallback, 4 launches; P overlaps dead hbf/wbf):
//   P/hbf/wbf 0..33.5MB | vlt 33.5..50.3MB | aL,vArr
// ---------------------------------------------------------------------------
extern "C" void kernel_launch(void* const* d_in, const int* in_sizes, int n_in,
                              void* d_out, int out_size, void* d_ws, size_t ws_size,
                              hipStream_t stream) {
  const float* hidden = (const float*)d_in[0];
  const float* mask   = (const float*)d_in[1];
  const float* vw     = (const float*)d_in[2];
  const float* vb     = (const float*)d_in[3];
  const float* U      = (const float*)d_in[4];
  const float* V      = (const float*)d_in[5];
  float* out = (float*)d_out;
  char* ws = (char*)d_ws;

  if (ws_size >= 69271552ull) {
    unsigned short* hbf = (unsigned short*)ws;
    unsigned short* wbf = (unsigned short*)(ws + 16777216);
    unsigned short* vlt = (unsigned short*)(ws + 18874368);
    unsigned short* P   = (unsigned short*)(ws + 35651584);
    float* aL   = (float*)(ws + 69206016);
    float* vArr = aL + 8192;
    fused_prep<<<640, 256, 0, stream>>>(hidden, U, V, vw, hbf, wbf, aL, vArr);
    gemm_stats<<<768, 256, 0, stream>>>(hbf, wbf, vb, vlt, aL, vArr, mask, P, 512);
    attn<<<512, 256, 0, stream>>>(P, vlt, out);
  } else {
    unsigned short* P   = (unsigned short*)ws;               // overlaps hbf/wbf
    unsigned short* hbf = (unsigned short*)ws;
    unsigned short* wbf = (unsigned short*)(ws + 16777216);
    unsigned short* vlt = (unsigned short*)(ws + 33554432);
    float* aL   = (float*)(ws + 50331648);
    float* vArr = aL + 8192;
    fused_prep<<<640, 256, 0, stream>>>(hidden, U, V, vw, hbf, wbf, aL, vArr);
    gemm_stats<<<512, 256, 0, stream>>>(hbf, wbf, vb, vlt, aL, vArr, mask, P, 512);
    gemm_stats<<<256, 256, 0, stream>>>(hbf, wbf, vb, vlt, aL, vArr, mask, P, 0);
    attn<<<512, 256, 0, stream>>>(P, vlt, out);
  }
}

// Round 9
// 157.707 us; speedup vs baseline: 1.2222x; 1.0690x over previous
//
#include <hip/hip_runtime.h>
#include <hip/hip_bf16.h>
#include <stdint.h>

#define LOG2E 1.44269504088896340736f

typedef float f32x4 __attribute__((ext_vector_type(4)));
typedef __bf16 bf16x8 __attribute__((ext_vector_type(8)));

__device__ __forceinline__ void g2lds16(const void* g, void* l) {
  __builtin_amdgcn_global_load_lds(
      (__attribute__((address_space(1))) unsigned int*)g,
      (__attribute__((address_space(3))) unsigned int*)l,
      16, 0, 0);
}

__device__ __forceinline__ unsigned short f2bf_u(float f) {
  __bf16 h = (__bf16)f;
  return __builtin_bit_cast(unsigned short, h);
}

// ---------------------------------------------------------------------------
// fused_prep: 640 blocks. pid<512: prep_hidden (barrier-free, 4 waves x 4
// rows, XCD-colocated row mapping). pid>=512: prep_w grid-stride bf16 cast.
// (unchanged from round 7 — measured-good)
// ---------------------------------------------------------------------------
__global__ void __launch_bounds__(256) fused_prep(
    const float* __restrict__ hidden, const float* __restrict__ U,
    const float* __restrict__ V, const float* __restrict__ vw,
    unsigned short* __restrict__ hbf, unsigned short* __restrict__ wbf,
    float* __restrict__ aL, float* __restrict__ vArr) {
  int tid = threadIdx.x;
  int pid = blockIdx.x;
  if (pid < 512) {
    int lane = tid & 63, w = tid >> 6;
    int xcd = pid & 7, idx = pid >> 3;
    int row0 = (xcd << 10) + (idx * 4 + w) * 4;
    float4 u4[4], v4[4];
#pragma unroll
    for (int c = 0; c < 4; ++c) {
      u4[c] = *(const float4*)&U[c * 256 + lane * 4];
      v4[c] = *(const float4*)&V[c * 256 + lane * 4];
    }
    float u_t = U[1024], v_t = V[1024];
    float su[4], sv[4];
#pragma unroll
    for (int r = 0; r < 4; ++r) {
      const float* hr = hidden + (size_t)(row0 + r) * 1024;
      unsigned short* hb = hbf + (size_t)(row0 + r) * 1024;
      float ssu = 0.f, ssv = 0.f;
#pragma unroll
      for (int c = 0; c < 4; ++c) {
        float4 x = *(const float4*)&hr[c * 256 + lane * 4];
        ushort4 o;
        o.x = f2bf_u(x.x); o.y = f2bf_u(x.y); o.z = f2bf_u(x.z); o.w = f2bf_u(x.w);
        *(ushort4*)&hb[c * 256 + lane * 4] = o;
        ssu += x.x * u4[c].x + x.y * u4[c].y + x.z * u4[c].z + x.w * u4[c].w;
        ssv += x.x * v4[c].x + x.y * v4[c].y + x.z * v4[c].z + x.w * v4[c].w;
      }
      su[r] = ssu; sv[r] = ssv;
    }
#pragma unroll
    for (int off = 1; off < 64; off <<= 1) {
#pragma unroll
      for (int r = 0; r < 4; ++r) {
        su[r] += __shfl_xor(su[r], off);
        sv[r] += __shfl_xor(sv[r], off);
      }
    }
    if (lane < 4) {
      int r = lane;
      float sur = (r == 0) ? su[0] : (r == 1) ? su[1] : (r == 2) ? su[2] : su[3];
      float svr = (r == 0) ? sv[0] : (r == 1) ? sv[1] : (r == 2) ? sv[2] : sv[3];
      aL[row0 + r] = (sur + u_t) * 0.125f * LOG2E;
      vArr[row0 + r] = svr + v_t;
    }
  } else {
    int wp = pid - 512;  // [0,128)
#pragma unroll
    for (int it = 0; it < 8; ++it) {
      int idx = (wp * 256 + tid) * 4 + it * 131072;
      float4 x = *(const float4*)&vw[idx];
      ushort4 o;
      o.x = f2bf_u(x.x); o.y = f2bf_u(x.y); o.z = f2bf_u(x.z); o.w = f2bf_u(x.w);
      *(ushort4*)&wbf[idx] = o;
    }
  }
}

// ---------------------------------------------------------------------------
// gemm_stats: pid < statsBlocks -> statsP (barrier-free, 4 waves x 8 rows),
// launched FIRST so the short stats work overlaps the gemm ramp instead of
// tailing it. pid >= statsBlocks -> gemm_vl, 128x128 tile, BK=128 (8 barrier
// pairs), 16-chunk XOR swizzle (phys = chunk ^ (row&15)), XCD-colocated.
// 256 ≡ 0 (mod 8) so the gemm XCD mapping is unchanged by the offset.
// ---------------------------------------------------------------------------
__global__ void __launch_bounds__(256) gemm_stats(
    const unsigned short* __restrict__ hbf, const unsigned short* __restrict__ wbf,
    const float* __restrict__ bias, unsigned short* __restrict__ vlt,
    const float* __restrict__ aL, const float* __restrict__ vArr,
    const float* __restrict__ mask, unsigned short* __restrict__ P,
    int statsBlocks) {
  __shared__ __align__(16) char sA[128 * 256];
  __shared__ __align__(16) char sB[128 * 256];
  int tid = threadIdx.x;
  int pid = blockIdx.x;
  if (pid >= statsBlocks) {
    int g = pid - statsBlocks;
    int lane = tid & 63, wave = tid >> 6;
    int xcd = g & 7, kk = g >> 3;
    int m0 = (xcd * 8 + (kk >> 3)) * 128;
    int n0 = (kk & 7) * 128;
    int rl = lane >> 4, pc = lane & 15;
    int wr = wave >> 1, wc = wave & 1;
    int m_ = lane & 15, q = lane >> 4;
    f32x4 acc[4][4] = {};
    for (int k0 = 0; k0 < 1024; k0 += 128) {
      __syncthreads();
#pragma unroll
      for (int ii = 0; ii < 8; ++ii) {
        int rb = wave * 32 + ii * 4;
        int r = rb + rl;
        int gc = pc ^ (r & 15);
        g2lds16(hbf + (size_t)(m0 + r) * 1024 + k0 + gc * 8, sA + rb * 256);
        g2lds16(wbf + (size_t)(n0 + r) * 1024 + k0 + gc * 8, sB + rb * 256);
      }
      __syncthreads();
#pragma unroll
      for (int ks = 0; ks < 4; ++ks) {
        bf16x8 af[4], bfr[4];
#pragma unroll
        for (int i = 0; i < 4; ++i)
          af[i] = *(const bf16x8*)(sA + (wr * 64 + i * 16 + m_) * 256 + (((ks * 4 + q) ^ m_) * 16));
#pragma unroll
        for (int j = 0; j < 4; ++j)
          bfr[j] = *(const bf16x8*)(sB + (wc * 64 + j * 16 + m_) * 256 + (((ks * 4 + q) ^ m_) * 16));
#pragma unroll
        for (int i = 0; i < 4; ++i)
#pragma unroll
          for (int j = 0; j < 4; ++j)
            acc[i][j] = __builtin_amdgcn_mfma_f32_16x16x32_bf16(af[i], bfr[j], acc[i][j], 0, 0, 0);
      }
    }
#pragma unroll
    for (int jt = 0; jt < 4; ++jt) {
      int j = n0 + wc * 64 + jt * 16 + m_;
      float bj = bias[j];
#pragma unroll
      for (int it = 0; it < 4; ++it) {
        int i = m0 + wr * 64 + it * 16 + q * 4;
        f32x4 a = acc[it][jt];
        ushort4 o;
        o.x = f2bf_u(a.x + bj); o.y = f2bf_u(a.y + bj);
        o.z = f2bf_u(a.z + bj); o.w = f2bf_u(a.w + bj);
        *(ushort4*)&vlt[(size_t)j * 8192 + i] = o;
      }
    }
  } else {
    // ---- statsP path: barrier-free, 4 waves x 8 rows, XCD-colocated ----
    int b = pid;
    int lane = tid & 63, w = tid >> 6;
    int xcd = b & 7, idx = b >> 3;               // idx in [0,32)
    int row0 = (xcd << 10) + (idx * 4 + w) * 8;  // 8 rows per wave
    int tb = (row0 >> 11) << 11;
    float4 va[8], ma[8];
#pragma unroll
    for (int c = 0; c < 4; ++c) {
      int t = c * 512 + lane * 8;
      va[2 * c]     = *(const float4*)&vArr[tb + t];
      va[2 * c + 1] = *(const float4*)&vArr[tb + t + 4];
      float4 m0v = *(const float4*)&mask[tb + t];
      float4 m1v = *(const float4*)&mask[tb + t + 4];
      ma[2 * c].x = m0v.x * LOG2E; ma[2 * c].y = m0v.y * LOG2E;
      ma[2 * c].z = m0v.z * LOG2E; ma[2 * c].w = m0v.w * LOG2E;
      ma[2 * c + 1].x = m1v.x * LOG2E; ma[2 * c + 1].y = m1v.y * LOG2E;
      ma[2 * c + 1].z = m1v.z * LOG2E; ma[2 * c + 1].w = m1v.w * LOG2E;
    }
#pragma unroll
    for (int r = 0; r < 8; ++r) {
      int row = row0 + r;
      float a = aL[row];
      float s[32];
#pragma unroll
      for (int qq = 0; qq < 8; ++qq) {
        s[qq * 4 + 0] = fmaf(a, va[qq].x, ma[qq].x);
        s[qq * 4 + 1] = fmaf(a, va[qq].y, ma[qq].y);
        s[qq * 4 + 2] = fmaf(a, va[qq].z, ma[qq].z);
        s[qq * 4 + 3] = fmaf(a, va[qq].w, ma[qq].w);
      }
      float mx = s[0];
#pragma unroll
      for (int u = 1; u < 32; ++u) mx = fmaxf(mx, s[u]);
#pragma unroll
      for (int off = 1; off < 64; off <<= 1) mx = fmaxf(mx, __shfl_xor(mx, off));
      float z = 0.f;
#pragma unroll
      for (int u = 0; u < 32; ++u) {
        s[u] = __builtin_amdgcn_exp2f(s[u] - mx);
        z += s[u];
      }
#pragma unroll
      for (int off = 1; off < 64; off <<= 1) z += __shfl_xor(z, off);
      float iz = __builtin_amdgcn_rcpf(z);
      unsigned short* pr = P + (size_t)row * 2048;
#pragma unroll
      for (int c = 0; c < 4; ++c) {
        bf16x8 o;
#pragma unroll
        for (int u = 0; u < 8; ++u) o[u] = (__bf16)(iz * s[c * 8 + u]);
        *(bf16x8*)&pr[c * 512 + lane * 8] = o;
      }
    }
  }
}

// ---------------------------------------------------------------------------
// attn: C = P' @ VL^T-slice, K=2048, BK=128 (8 barrier pairs vs 16 at BK=64).
// 512 blocks (grid-limited 2/CU, so 64KB LDS costs no occupancy), 128x128
// tile, 16-chunk XOR swizzle, XCD swizzle as before.
// ---------------------------------------------------------------------------
__global__ void __launch_bounds__(256) attn(
    const unsigned short* __restrict__ p, const unsigned short* __restrict__ vlt,
    float* __restrict__ out) {
  __shared__ __align__(16) char sA[128 * 256];
  __shared__ __align__(16) char sB[128 * 256];
  int tid = threadIdx.x;
  int lane = tid & 63, wave = tid >> 6;
  int pid = blockIdx.x;
  int xcd = pid & 7, kk = pid >> 3;
  int i0 = (xcd * 8 + (kk >> 3)) * 128;  // s-row tile (batch-major)
  int h0 = (kk & 7) * 128;               // h tile
  int b = i0 >> 11;
  size_t toff = (size_t)b << 11;
  int rl = lane >> 4, pc = lane & 15;
  int wr = wave >> 1, wc = wave & 1;
  int m_ = lane & 15, q = lane >> 4;
  f32x4 acc[4][4] = {};
  for (int k0 = 0; k0 < 2048; k0 += 128) {
    __syncthreads();
#pragma unroll
    for (int ii = 0; ii < 8; ++ii) {
      int rb = wave * 32 + ii * 4;
      int r = rb + rl;
      int gc = pc ^ (r & 15);
      g2lds16(p + (size_t)(i0 + r) * 2048 + k0 + gc * 8, sA + rb * 256);
      g2lds16(vlt + (size_t)(h0 + r) * 8192 + toff + k0 + gc * 8, sB + rb * 256);
    }
    __syncthreads();
#pragma unroll
    for (int ks = 0; ks < 4; ++ks) {
      bf16x8 af[4], bfr[4];
#pragma unroll
      for (int i = 0; i < 4; ++i)
        af[i] = *(const bf16x8*)(sA + (wr * 64 + i * 16 + m_) * 256 + (((ks * 4 + q) ^ m_) * 16));
#pragma unroll
      for (int j = 0; j < 4; ++j)
        bfr[j] = *(const bf16x8*)(sB + (wc * 64 + j * 16 + m_) * 256 + (((ks * 4 + q) ^ m_) * 16));
#pragma unroll
      for (int i = 0; i < 4; ++i)
#pragma unroll
        for (int j = 0; j < 4; ++j)
          acc[i][j] = __builtin_amdgcn_mfma_f32_16x16x32_bf16(af[i], bfr[j], acc[i][j], 0, 0, 0);
    }
  }
#pragma unroll
  for (int it = 0; it < 4; ++it) {
    int gi = i0 + wr * 64 + it * 16 + q * 4;
#pragma unroll
    for (int jt = 0; jt < 4; ++jt) {
      int h = h0 + wc * 64 + jt * 16 + m_;
      f32x4 a = acc[it][jt];
      out[(size_t)(gi + 0) * 1024 + h] = a.x;
      out[(size_t)(gi + 1) * 1024 + h] = a.y;
      out[(size_t)(gi + 2) * 1024 + h] = a.z;
      out[(size_t)(gi + 3) * 1024 + h] = a.w;
    }
  }
}

// ---------------------------------------------------------------------------
// Layout A (ws >= 69.3 MB, 3 launches; P disjoint so statsP overlaps gemm):
//   hbf 0..16MB | wbf 16..18MB | vlt 18..34.8MB | P 34.8..68.3MB | aL,vArr
// Layout B (fallback, 4 launches; P overlaps dead hbf/wbf).
// ---------------------------------------------------------------------------
extern "C" void kernel_launch(void* const* d_in, const int* in_sizes, int n_in,
                              void* d_out, int out_size, void* d_ws, size_t ws_size,
                              hipStream_t stream) {
  const float* hidden = (const float*)d_in[0];
  const float* mask   = (const float*)d_in[1];
  const float* vw     = (const float*)d_in[2];
  const float* vb     = (const float*)d_in[3];
  const float* U      = (const float*)d_in[4];
  const float* V      = (const float*)d_in[5];
  float* out = (float*)d_out;
  char* ws = (char*)d_ws;

  if (ws_size >= 69271552ull) {
    unsigned short* hbf = (unsigned short*)ws;
    unsigned short* wbf = (unsigned short*)(ws + 16777216);
    unsigned short* vlt = (unsigned short*)(ws + 18874368);
    unsigned short* P   = (unsigned short*)(ws + 35651584);
    float* aL   = (float*)(ws + 69206016);
    float* vArr = aL + 8192;
    fused_prep<<<640, 256, 0, stream>>>(hidden, U, V, vw, hbf, wbf, aL, vArr);
    gemm_stats<<<768, 256, 0, stream>>>(hbf, wbf, vb, vlt, aL, vArr, mask, P, 256);
    attn<<<512, 256, 0, stream>>>(P, vlt, out);
  } else {
    unsigned short* hbf = (unsigned short*)ws;
    unsigned short* wbf = (unsigned short*)(ws + 16777216);
    unsigned short* P   = (unsigned short*)ws;               // overlaps dead hbf/wbf
    unsigned short* vlt = (unsigned short*)(ws + 33554432);
    float* aL   = (float*)(ws + 50331648);
    float* vArr = aL + 8192;
    fused_prep<<<640, 256, 0, stream>>>(hidden, U, V, vw, hbf, wbf, aL, vArr);
    gemm_stats<<<512, 256, 0, stream>>>(hbf, wbf, vb, vlt, aL, vArr, mask, P, 0);
    gemm_stats<<<256, 256, 0, stream>>>(hbf, wbf, vb, vlt, aL, vArr, mask, P, 256);
    attn<<<512, 256, 0, stream>>>(P, vlt, out);
  }
}